// Round 1
// baseline (845.861 us; speedup 1.0000x reference)
//
#include <hip/hip_runtime.h>

// CRF forward (linear-chain, partition function) on MI355X.
// B=256 chains -> 256 blocks (1/CU). 128 threads: thread i owns state i,
// E-row exp(trans[i,:]) in 128 VGPRs, score s_i in a register.
// Per step: ONE barrier (p + wave-max double-buffered in LDS),
// dot via broadcast float4 LDS reads + 8-accumulator FMA chain.
// Stale-by-1 max offset keeps exp() in range (drift <= ~15 per step).

static constexpr int BB  = 256;
static constexpr int SS  = 1024;
static constexpr int TT  = 128;
static constexpr int KCH = 16;          // h prefetch chunk (amortize barrier vmcnt drain)
#define NEGV (-10000.0f)

__device__ __forceinline__ float wave_max(float v) {
    #pragma unroll
    for (int o = 32; o > 0; o >>= 1) v = fmaxf(v, __shfl_xor(v, o, 64));
    return v;
}
__device__ __forceinline__ float wave_sum(float v) {
    #pragma unroll
    for (int o = 32; o > 0; o >>= 1) v += __shfl_xor(v, o, 64);
    return v;
}

__global__ __launch_bounds__(TT, 1) void crf_fwd_kernel(
        const float* __restrict__ h, const float* __restrict__ mask,
        const float* __restrict__ trans, float* __restrict__ out) {
    const int b    = blockIdx.x;
    const int i    = threadIdx.x;       // state index (row of trans)
    const int lane = i & 63;
    const int wid  = i >> 6;

    __shared__ float ps[2][TT];         // p = exp(score - off), double-buffered
    __shared__ float red[2][2];         // per-wave max partials, double-buffered

    // ---- E row i = exp(trans[i,:]) into 128 VGPRs (one-time)
    float Ereg[TT];
    {
        const float4* tr4 = reinterpret_cast<const float4*>(trans + i * TT);
        #pragma unroll
        for (int q = 0; q < TT / 4; ++q) {
            float4 v = tr4[q];
            Ereg[4*q+0] = __expf(v.x);
            Ereg[4*q+1] = __expf(v.y);
            Ereg[4*q+2] = __expf(v.z);
            Ereg[4*q+3] = __expf(v.w);
        }
    }

    // ---- len = sum(mask[b,:])  (mask is monotone 1..1 0..0)
    const float* mrow = mask + b * SS;
    float c = 0.f;
    #pragma unroll
    for (int t = 0; t < SS / TT; ++t) c += mrow[t * TT + i];
    c = wave_sum(c);
    if (lane == 0) red[0][wid] = c;
    __syncthreads();
    const int len = (int)(red[0][0] + red[0][1] + 0.5f);
    __syncthreads();   // protect red[0] before main loop reuses it

    // ---- init: score0 = NEG except SOS(=0) -> 0 ; off = max(score0) = 0
    float s   = (i == 0) ? 0.0f : NEGV;
    float off = 0.0f;
    const float* hbase = h + ((size_t)b * SS) * TT + i;

    for (int t0 = 0; t0 < len; t0 += KCH) {
        // prefetch KCH steps of h (batched so the per-barrier vmcnt(0)
        // drain stalls once per chunk, not once per step)
        float hbuf[KCH];
        #pragma unroll
        for (int k = 0; k < KCH; ++k) {
            int t = t0 + k; t = (t < SS) ? t : SS - 1;
            hbuf[k] = hbase[t * TT];
        }
        #pragma unroll
        for (int k = 0; k < KCH; ++k) {
            const int t   = t0 + k;
            const int buf = t & 1;
            // W phase: publish p and wave-max partials
            ps[buf][i] = __expf(s - off);
            float wm = wave_max(s);
            if (lane == 0) red[buf][wid] = wm;
            __syncthreads();            // the ONLY barrier per step
            // R phase
            const float offn = fmaxf(red[buf][0], red[buf][1]);   // max of s^(t), used at t+1
            const float4* p4 = reinterpret_cast<const float4*>(ps[buf]);
            float a0=0,a1=0,a2=0,a3=0,a4=0,a5=0,a6=0,a7=0;
            #pragma unroll
            for (int q = 0; q < TT / 4; q += 2) {
                float4 v0 = p4[q];
                float4 v1 = p4[q + 1];
                a0 = fmaf(Ereg[4*q+0], v0.x, a0);
                a1 = fmaf(Ereg[4*q+1], v0.y, a1);
                a2 = fmaf(Ereg[4*q+2], v0.z, a2);
                a3 = fmaf(Ereg[4*q+3], v0.w, a3);
                a4 = fmaf(Ereg[4*q+4], v1.x, a4);
                a5 = fmaf(Ereg[4*q+5], v1.y, a5);
                a6 = fmaf(Ereg[4*q+6], v1.z, a6);
                a7 = fmaf(Ereg[4*q+7], v1.w, a7);
            }
            float sum  = ((a0 + a1) + (a2 + a3)) + ((a4 + a5) + (a6 + a7));
            float snew = hbuf[k] + off + __logf(sum);
            if (t < len) s = snew;      // tail-of-chunk predication (len is block-uniform)
            off = offn;
        }
    }

    __syncthreads();
    // ---- epilogue: out[b] = logsumexp_j(s_j + trans[EOS, j]), EOS = 1
    float v  = s + trans[1 * TT + i];
    float wm = wave_max(v);
    if (lane == 0) red[0][wid] = wm;
    __syncthreads();
    const float m = fmaxf(red[0][0], red[0][1]);
    float e = wave_sum(__expf(v - m));
    if (lane == 0) red[1][wid] = e;
    __syncthreads();
    if (i == 0) out[b] = m + __logf(red[1][0] + red[1][1]);
}

extern "C" void kernel_launch(void* const* d_in, const int* in_sizes, int n_in,
                              void* d_out, int out_size, void* d_ws, size_t ws_size,
                              hipStream_t stream) {
    const float* h     = (const float*)d_in[0];
    const float* mask  = (const float*)d_in[1];
    const float* trans = (const float*)d_in[2];
    float* out         = (float*)d_out;
    crf_fwd_kernel<<<dim3(BB), dim3(TT), 0, stream>>>(h, mask, trans, out);
}

// Round 2
// 661.401 us; speedup vs baseline: 1.2789x; 1.2789x over previous
//
#include <hip/hip_runtime.h>

// CRF forward scan, one WAVE per chain (no barriers at all).
// 256 blocks x 64 threads; lane l owns states (2l, 2l+1).
// Per step:
//   fresh max m of s over 128 states  : 6-shuffle butterfly (in-wave)
//   p = exp(s - m) in [0,1]           : packed to f16x2, ONE ds_write_b32
//   (compiler fence; same-wave DS ops are processed in order -> no barrier)
//   read all p: 16x ds_read_b128 broadcast (16KB/step replicated, 4x less
//   than fp32), dot via v_dot2_f32_f16: 64 dot2 per state row, fp32 accum.
//   s' = h + m + log(dot)
// h prefetched 8 steps deep; with no barriers there is no vmcnt(0) drain,
// so loads stay in flight under compute.
// E = exp(trans) rows held as 128 packed-f16x2 VGPRs per lane (one-time).

typedef _Float16 h2 __attribute__((ext_vector_type(2)));

static constexpr int BB = 256, SS = 1024, TT = 128, HCH = 8;
#define NEGV (-10000.0f)

__device__ __forceinline__ float dot2f(h2 a, h2 b, float c) {
#if __has_builtin(__builtin_amdgcn_fdot2)
    return __builtin_amdgcn_fdot2(a, b, c, false);
#else
    return fmaf((float)a.x, (float)b.x, fmaf((float)a.y, (float)b.y, c));
#endif
}

__global__ __launch_bounds__(64, 1) void crf_wave_kernel(
        const float* __restrict__ h, const float* __restrict__ mask,
        const float* __restrict__ trans, float* __restrict__ out) {
    const int b = blockIdx.x;
    const int l = threadIdx.x;          // 0..63
    const int i0 = 2 * l, i1 = i0 + 1;  // owned states

    __shared__ alignas(16) unsigned p2[2][64];   // packed f16x2, double-buffered

    // ---- one-time: E rows i0,i1 = exp(trans[row,:]) as 64 packed f16x2 each
    h2 E0[64], E1[64];
    {
        const float4* r0 = reinterpret_cast<const float4*>(trans + (size_t)i0 * TT);
        const float4* r1 = reinterpret_cast<const float4*>(trans + (size_t)i1 * TT);
        #pragma unroll
        for (int q = 0; q < 32; ++q) {
            float4 a = r0[q], c = r1[q];
            E0[2*q]   = h2{(_Float16)__expf(a.x), (_Float16)__expf(a.y)};
            E0[2*q+1] = h2{(_Float16)__expf(a.z), (_Float16)__expf(a.w)};
            E1[2*q]   = h2{(_Float16)__expf(c.x), (_Float16)__expf(c.y)};
            E1[2*q+1] = h2{(_Float16)__expf(c.z), (_Float16)__expf(c.w)};
        }
    }

    // ---- len = sum(mask[b,:]) (mask monotone)
    const float* mrow = mask + (size_t)b * SS;
    float cnt = 0.f;
    #pragma unroll
    for (int t = 0; t < SS / 64; ++t) cnt += mrow[t * 64 + l];
    #pragma unroll
    for (int o = 32; o; o >>= 1) cnt += __shfl_xor(cnt, o, 64);
    const int len = (int)(cnt + 0.5f);

    // ---- init (SOS=0 lives in lane 0 slot 0)
    float s0 = (l == 0) ? 0.0f : NEGV;
    float s1 = NEGV;
    const float* hb = h + ((size_t)b * SS) * TT + i0;

    for (int t0 = 0; t0 < len; t0 += HCH) {
        float2 hbuf[HCH];
        #pragma unroll
        for (int k = 0; k < HCH; ++k) {
            int t = t0 + k; t = (t < SS) ? t : (SS - 1);
            hbuf[k] = *reinterpret_cast<const float2*>(hb + (size_t)t * TT);
        }
        #pragma unroll
        for (int k = 0; k < HCH; ++k) {
            const int t = t0 + k;
            // fresh max over all 128 states (in-wave butterfly)
            float m = fmaxf(s0, s1);
            #pragma unroll
            for (int o = 32; o; o >>= 1) m = fmaxf(m, __shfl_xor(m, o, 64));
            // publish p = exp(s-m) as f16x2 (exact max -> p in [0,1])
            h2 pp = h2{(_Float16)__expf(s0 - m), (_Float16)__expf(s1 - m)};
            const int buf = t & 1;
            p2[buf][l] = __builtin_bit_cast(unsigned, pp);
            asm volatile("" ::: "memory");   // compiler fence; HW DS ops are in-order per wave
            // dot: each lane needs all 128 p's (broadcast b128 reads)
            const uint4* pv = reinterpret_cast<const uint4*>(p2[buf]);
            float a0=0,a1=0,a2=0,a3=0, c0=0,c1=0,c2=0,c3=0;
            #pragma unroll
            for (int q = 0; q < 16; ++q) {
                uint4 v = pv[q];
                h2 px = __builtin_bit_cast(h2, v.x);
                h2 py = __builtin_bit_cast(h2, v.y);
                h2 pz = __builtin_bit_cast(h2, v.z);
                h2 pw = __builtin_bit_cast(h2, v.w);
                a0 = dot2f(E0[4*q+0], px, a0);
                a1 = dot2f(E0[4*q+1], py, a1);
                a2 = dot2f(E0[4*q+2], pz, a2);
                a3 = dot2f(E0[4*q+3], pw, a3);
                c0 = dot2f(E1[4*q+0], px, c0);
                c1 = dot2f(E1[4*q+1], py, c1);
                c2 = dot2f(E1[4*q+2], pz, c2);
                c3 = dot2f(E1[4*q+3], pw, c3);
            }
            float ns0 = hbuf[k].x + m + __logf((a0 + a1) + (a2 + a3));
            float ns1 = hbuf[k].y + m + __logf((c0 + c1) + (c2 + c3));
            if (t < len) { s0 = ns0; s1 = ns1; }   // chunk-tail predication
        }
    }

    // ---- epilogue: out[b] = logsumexp(s + trans[EOS,:]), EOS = 1
    float v0 = s0 + trans[1 * TT + i0];
    float v1 = s1 + trans[1 * TT + i1];
    float mm = fmaxf(v0, v1);
    #pragma unroll
    for (int o = 32; o; o >>= 1) mm = fmaxf(mm, __shfl_xor(mm, o, 64));
    float e = __expf(v0 - mm) + __expf(v1 - mm);
    #pragma unroll
    for (int o = 32; o; o >>= 1) e += __shfl_xor(e, o, 64);
    if (l == 0) out[b] = mm + __logf(e);
}

extern "C" void kernel_launch(void* const* d_in, const int* in_sizes, int n_in,
                              void* d_out, int out_size, void* d_ws, size_t ws_size,
                              hipStream_t stream) {
    const float* h     = (const float*)d_in[0];
    const float* mask  = (const float*)d_in[1];
    const float* trans = (const float*)d_in[2];
    float* out         = (float*)d_out;
    crf_wave_kernel<<<dim3(BB), dim3(64), 0, stream>>>(h, mask, trans, out);
}

// Round 3
// 483.778 us; speedup vs baseline: 1.7484x; 1.3672x over previous
//
#include <hip/hip_runtime.h>

// CRF forward scan, one WAVE per chain, no barriers.
// R3 changes vs R2:
//  - fresh-max reduce via DPP (VALU pipe, ~50cy) instead of 6 serial
//    ds_bpermute shuffles (~350cy) -- the max sits on the critical path
//    s -> max -> exp -> ds_write -> ds_read -> dot -> log -> s'.
//  - h prefetch double-buffered across 8-step chunks: loads issued one
//    chunk ahead, first use >= ~3000cy after issue (HBM latency hidden).
// Kept: lane l owns states (2l,2l+1); E=exp(trans) rows in 128 packed-f16x2
// regs; p published as f16x2 (one ds_write_b32), read back as 16x
// broadcast ds_read_b128 (conflict-free); dot via v_dot2_f32_f16, fp32 accum.

typedef _Float16 h2 __attribute__((ext_vector_type(2)));

static constexpr int BB = 256, SS = 1024, TT = 128, HCH = 8;
#define NEGV (-10000.0f)

__device__ __forceinline__ float dot2f(h2 a, h2 b, float c) {
    return __builtin_amdgcn_fdot2(a, b, c, false);
}

// Full-wave (64-lane) max via gfx9 DPP reduction; result broadcast via
// readlane(63). All VALU-pipe, no LDS counter traffic.
__device__ __forceinline__ float wave_max_dpp(float v) {
    int x, y;
    x = __builtin_bit_cast(int, v);
    y = __builtin_amdgcn_update_dpp(x, x, 0xB1, 0xF, 0xF, false);   // quad_perm [1,0,3,2]
    v = fmaxf(v, __builtin_bit_cast(float, y));
    x = __builtin_bit_cast(int, v);
    y = __builtin_amdgcn_update_dpp(x, x, 0x4E, 0xF, 0xF, false);   // quad_perm [2,3,0,1]
    v = fmaxf(v, __builtin_bit_cast(float, y));
    x = __builtin_bit_cast(int, v);
    y = __builtin_amdgcn_update_dpp(x, x, 0x141, 0xF, 0xF, false);  // row_half_mirror
    v = fmaxf(v, __builtin_bit_cast(float, y));
    x = __builtin_bit_cast(int, v);
    y = __builtin_amdgcn_update_dpp(x, x, 0x140, 0xF, 0xF, false);  // row_mirror
    v = fmaxf(v, __builtin_bit_cast(float, y));
    x = __builtin_bit_cast(int, v);
    y = __builtin_amdgcn_update_dpp(x, x, 0x142, 0xA, 0xF, false);  // row_bcast15 -> rows 1,3
    v = fmaxf(v, __builtin_bit_cast(float, y));
    x = __builtin_bit_cast(int, v);
    y = __builtin_amdgcn_update_dpp(x, x, 0x143, 0xC, 0xF, false);  // row_bcast31 -> rows 2,3
    v = fmaxf(v, __builtin_bit_cast(float, y));
    // lane 63 now holds the full-wave max
    return __builtin_bit_cast(float,
        __builtin_amdgcn_readlane(__builtin_bit_cast(int, v), 63));
}

__global__ __launch_bounds__(64, 1) void crf_wave_kernel(
        const float* __restrict__ h, const float* __restrict__ mask,
        const float* __restrict__ trans, float* __restrict__ out) {
    const int b = blockIdx.x;
    const int l = threadIdx.x;          // 0..63
    const int i0 = 2 * l, i1 = i0 + 1;  // owned states

    __shared__ alignas(16) unsigned p2[2][64];   // packed f16x2, double-buffered

    // ---- one-time: E rows i0,i1 = exp(trans[row,:]) as 64 packed f16x2 each
    h2 E0[64], E1[64];
    {
        const float4* r0 = reinterpret_cast<const float4*>(trans + (size_t)i0 * TT);
        const float4* r1 = reinterpret_cast<const float4*>(trans + (size_t)i1 * TT);
        #pragma unroll
        for (int q = 0; q < 32; ++q) {
            float4 a = r0[q], c = r1[q];
            E0[2*q]   = h2{(_Float16)__expf(a.x), (_Float16)__expf(a.y)};
            E0[2*q+1] = h2{(_Float16)__expf(a.z), (_Float16)__expf(a.w)};
            E1[2*q]   = h2{(_Float16)__expf(c.x), (_Float16)__expf(c.y)};
            E1[2*q+1] = h2{(_Float16)__expf(c.z), (_Float16)__expf(c.w)};
        }
    }

    // ---- len = sum(mask[b,:]) (mask monotone)
    const float* mrow = mask + (size_t)b * SS;
    float cnt = 0.f;
    #pragma unroll
    for (int t = 0; t < SS / 64; ++t) cnt += mrow[t * 64 + l];
    #pragma unroll
    for (int o = 32; o; o >>= 1) cnt += __shfl_xor(cnt, o, 64);
    const int len = (int)(cnt + 0.5f);

    // ---- init (SOS=0 lives in lane 0 slot 0)
    float s0 = (l == 0) ? 0.0f : NEGV;
    float s1 = NEGV;
    const float* hb = h + ((size_t)b * SS) * TT + i0;

    auto load_chunk = [&](float2* buf, int tbase) {
        #pragma unroll
        for (int k = 0; k < HCH; ++k) {
            int t = tbase + k; t = (t < SS) ? t : (SS - 1);
            buf[k] = *reinterpret_cast<const float2*>(hb + (size_t)t * TT);
        }
    };

    auto step = [&](float2 hk, int t) {
        // fresh max over all 128 states: 1 fmax + 6 DPP levels (VALU pipe)
        const float m = wave_max_dpp(fmaxf(s0, s1));
        // publish p = exp(s-m) as f16x2 (exact max -> p in [0,1])
        h2 pp = h2{(_Float16)__expf(s0 - m), (_Float16)__expf(s1 - m)};
        const int buf = t & 1;
        p2[buf][l] = __builtin_bit_cast(unsigned, pp);
        asm volatile("" ::: "memory");   // same-wave DS ops are in-order
        // dot: each lane needs all 128 p's (broadcast b128 reads)
        const uint4* pv = reinterpret_cast<const uint4*>(p2[buf]);
        float a0=0,a1=0,a2=0,a3=0, c0=0,c1=0,c2=0,c3=0;
        #pragma unroll
        for (int q = 0; q < 16; ++q) {
            uint4 v = pv[q];
            h2 px = __builtin_bit_cast(h2, v.x);
            h2 py = __builtin_bit_cast(h2, v.y);
            h2 pz = __builtin_bit_cast(h2, v.z);
            h2 pw = __builtin_bit_cast(h2, v.w);
            a0 = dot2f(E0[4*q+0], px, a0);
            a1 = dot2f(E0[4*q+1], py, a1);
            a2 = dot2f(E0[4*q+2], pz, a2);
            a3 = dot2f(E0[4*q+3], pw, a3);
            c0 = dot2f(E1[4*q+0], px, c0);
            c1 = dot2f(E1[4*q+1], py, c1);
            c2 = dot2f(E1[4*q+2], pz, c2);
            c3 = dot2f(E1[4*q+3], pw, c3);
        }
        float ns0 = hk.x + m + __logf((a0 + a1) + (a2 + a3));
        float ns1 = hk.y + m + __logf((c0 + c1) + (c2 + c3));
        if (t < len) { s0 = ns0; s1 = ns1; }   // wave-uniform predicate
    };

    // ---- main scan: h double-buffered one chunk ahead
    float2 hA[HCH], hB[HCH];
    load_chunk(hA, 0);
    for (int t0 = 0; t0 < len; t0 += 2 * HCH) {
        load_chunk(hB, t0 + HCH);
        #pragma unroll
        for (int k = 0; k < HCH; ++k) step(hA[k], t0 + k);
        load_chunk(hA, t0 + 2 * HCH);
        #pragma unroll
        for (int k = 0; k < HCH; ++k) step(hB[k], t0 + HCH + k);
    }

    // ---- epilogue: out[b] = logsumexp(s + trans[EOS,:]), EOS = 1
    float v0 = s0 + trans[1 * TT + i0];
    float v1 = s1 + trans[1 * TT + i1];
    float mm = fmaxf(v0, v1);
    #pragma unroll
    for (int o = 32; o; o >>= 1) mm = fmaxf(mm, __shfl_xor(mm, o, 64));
    float e = __expf(v0 - mm) + __expf(v1 - mm);
    #pragma unroll
    for (int o = 32; o; o >>= 1) e += __shfl_xor(e, o, 64);
    if (l == 0) out[b] = mm + __logf(e);
}

extern "C" void kernel_launch(void* const* d_in, const int* in_sizes, int n_in,
                              void* d_out, int out_size, void* d_ws, size_t ws_size,
                              hipStream_t stream) {
    const float* h     = (const float*)d_in[0];
    const float* mask  = (const float*)d_in[1];
    const float* trans = (const float*)d_in[2];
    float* out         = (float*)d_out;
    crf_wave_kernel<<<dim3(BB), dim3(64), 0, stream>>>(h, mask, trans, out);
}